// Round 10
// baseline (434.067 us; speedup 1.0000x reference)
//
#include <hip/hip_runtime.h>
#include <hip/hip_bf16.h>
#include <math.h>

typedef __bf16 bf16_t;
typedef __fp16 f16_t;
typedef __attribute__((ext_vector_type(8))) __bf16 bf16x8;
typedef __attribute__((ext_vector_type(4))) __bf16 bf16x4;
typedef __attribute__((ext_vector_type(4))) __fp16 f16x4;
typedef __attribute__((ext_vector_type(4))) float f32x4;

// ---------------------------------------------------------------------------
// Row compaction: idx[0..Mc) = enabled row ids, *McPtr = Mc.
// ---------------------------------------------------------------------------
__global__ __launch_bounds__(256) void compact_kernel(
    const int* __restrict__ qen, int* __restrict__ idx, int* __restrict__ McPtr)
{
  __shared__ int cnts[256];
  int t = threadIdx.x;
  int flags[16], c = 0;
#pragma unroll
  for (int i = 0; i < 16; ++i) {
    flags[i] = qen[t * 16 + i] != 0;
    c += flags[i];
  }
  cnts[t] = c;
  __syncthreads();
  for (int off = 1; off < 256; off <<= 1) {
    int v = cnts[t];
    if (t >= off) v += cnts[t - off];
    __syncthreads();
    cnts[t] = v;
    __syncthreads();
  }
  int p = cnts[t] - c;
  int total = cnts[255];
#pragma unroll
  for (int i = 0; i < 16; ++i)
    if (flags[i]) idx[p++] = t * 16 + i;
  if (t == 0) *McPtr = total;
  for (int j = total + t; j < 4096; j += 256) idx[j] = 0;
}

// ---------------------------------------------------------------------------
// Disabled rows: out[row] = q_x[row].
// ---------------------------------------------------------------------------
__global__ __launch_bounds__(256) void copy_disabled_kernel(
    const int* __restrict__ qen, const float* __restrict__ qx,
    float* __restrict__ out)
{
  int row = blockIdx.x;
  if (qen[row]) return;
  int tid = threadIdx.x;
  ((float4*)(out + (size_t)row * 1024))[tid] =
      ((const float4*)(qx + (size_t)row * 1024))[tid];
}

// ---------------------------------------------------------------------------
// mod init + partial (split-K atomics)
// ---------------------------------------------------------------------------
__global__ __launch_bounds__(256) void mod_init_kernel(
    const float* __restrict__ adab, float* __restrict__ mod)
{
  int i = blockIdx.x * 256 + threadIdx.x;
  mod[i] = adab[i % 6144];
}

__global__ __launch_bounds__(256) void mod_partial_kernel(
    const float* __restrict__ tc, const float* __restrict__ adaW,
    float* __restrict__ mod)
{
  __shared__ float st[4][128];
  int tid = threadIdx.x, z = blockIdx.y;
  for (int i = tid; i < 512; i += 256)
    st[i >> 7][i & 127] = tc[(i >> 7) * 1024 + z * 128 + (i & 127)];
  __syncthreads();
  int col = blockIdx.x * 256 + tid;
  float a0 = 0.f, a1 = 0.f, a2 = 0.f, a3 = 0.f;
  for (int k = 0; k < 128; ++k) {
    float wv = adaW[(size_t)(z * 128 + k) * 6144 + col];
    a0 = fmaf(st[0][k], wv, a0);
    a1 = fmaf(st[1][k], wv, a1);
    a2 = fmaf(st[2][k], wv, a2);
    a3 = fmaf(st[3][k], wv, a3);
  }
  atomicAdd(&mod[col], a0);
  atomicAdd(&mod[6144 + col], a1);
  atomicAdd(&mod[2 * 6144 + col], a2);
  atomicAdd(&mod[3 * 6144 + col], a3);
}

// ---------------------------------------------------------------------------
// All five weight transposes (f32 -> bf16) in one launch.
// ---------------------------------------------------------------------------
__global__ __launch_bounds__(256) void transpose_all(
    const float* __restrict__ Wq, const float* __restrict__ Wkv,
    const float* __restrict__ Wo, const float* __restrict__ W1,
    const float* __restrict__ W2,
    bf16_t* __restrict__ oWq, bf16_t* __restrict__ oWkv,
    bf16_t* __restrict__ oWo, bf16_t* __restrict__ oW1,
    bf16_t* __restrict__ oW2)
{
  __shared__ float tile[32][33];
  int bid = blockIdx.x;
  const float* in; bf16_t* out; int R, C, gx, local;
  if (bid < 1024)      { in = Wq;  out = oWq;  R = 1024; C = 1024; gx = 32;  local = bid; }
  else if (bid < 3072) { in = Wkv; out = oWkv; R = 1024; C = 2048; gx = 64;  local = bid - 1024; }
  else if (bid < 4096) { in = Wo;  out = oWo;  R = 1024; C = 1024; gx = 32;  local = bid - 3072; }
  else if (bid < 8192) { in = W1;  out = oW1;  R = 1024; C = 4096; gx = 128; local = bid - 4096; }
  else                 { in = W2;  out = oW2;  R = 4096; C = 1024; gx = 32;  local = bid - 8192; }
  int c0 = (local % gx) * 32, r0 = (local / gx) * 32;
  int tx = threadIdx.x, ty = threadIdx.y;
#pragma unroll
  for (int i = 0; i < 4; ++i)
    tile[ty + i * 8][tx] = in[(size_t)(r0 + ty + i * 8) * C + c0 + tx];
  __syncthreads();
#pragma unroll
  for (int i = 0; i < 4; ++i)
    out[(size_t)(c0 + ty + i * 8) * R + r0 + tx] = (bf16_t)tile[tx][ty + i * 8];
}

// ---------------------------------------------------------------------------
// Both input LayerNorms in one launch.
// ---------------------------------------------------------------------------
__global__ __launch_bounds__(256) void ln_both_kernel(
    const float* __restrict__ qx, const float* __restrict__ kvx,
    const float* __restrict__ qnw, const float* __restrict__ kvnw,
    const float* __restrict__ mod,
    bf16_t* __restrict__ qn_out, bf16_t* __restrict__ kvn_out)
{
  int rowg = blockIdx.x;
  bool isQ = rowg < 4096;
  int row = isQ ? rowg : rowg - 4096;
  int b = row >> 10;
  int tid = threadIdx.x;
  const float* x = (isQ ? qx : kvx) + (size_t)row * 1024;
  const float* wgt = isQ ? qnw : kvnw;
  bf16_t* outp = (isQ ? qn_out : kvn_out) + (size_t)row * 1024;

  float4 v = ((const float4*)x)[tid];
  float s = v.x + v.y + v.z + v.w;
  float s2 = v.x * v.x + v.y * v.y + v.z * v.z + v.w * v.w;
#pragma unroll
  for (int off = 32; off > 0; off >>= 1) {
    s += __shfl_down(s, off, 64);
    s2 += __shfl_down(s2, off, 64);
  }
  __shared__ float ps[4], ps2[4];
  if ((tid & 63) == 0) { ps[tid >> 6] = s; ps2[tid >> 6] = s2; }
  __syncthreads();
  float mu = (ps[0] + ps[1] + ps[2] + ps[3]) * (1.0f / 1024.0f);
  float var = (ps2[0] + ps2[1] + ps2[2] + ps2[3]) * (1.0f / 1024.0f) - mu * mu;
  float rs = rsqrtf(var + 1e-5f);
  float xv[4] = {v.x, v.y, v.z, v.w};
#pragma unroll
  for (int i = 0; i < 4; ++i) {
    int col = tid * 4 + i;
    float n = (xv[i] - mu) * rs * wgt[col];
    if (isQ)
      n = n * (1.0f + mod[b * 6144 + 1024 + col]) + mod[b * 6144 + col];
    outp[col] = (bf16_t)n;
  }
}

// ---------------------------------------------------------------------------
// Reduce split-K bf16 partials of Q proj + RoPE + scale -> q_r (B,H,S,64)
// ---------------------------------------------------------------------------
__global__ __launch_bounds__(256) void reduce_q_rope_kernel(
    const bf16_t* __restrict__ P0, const bf16_t* __restrict__ P1,
    const float* __restrict__ cosq, const float* __restrict__ sinq,
    bf16_t* __restrict__ qr)
{
  int t = blockIdx.x * 256 + threadIdx.x;
  int hd = t & 31;
  int h = (t >> 5) & 15;
  int s = (t >> 9) & 1023;
  int b = t >> 19;
  size_t base = ((size_t)(b * 1024 + s)) * 1024 + h * 64 + hd;
  float v1 = (float)P0[base] + (float)P1[base];
  float v2 = (float)P0[base + 32] + (float)P1[base + 32];
  float c1 = cosq[s * 64 + hd], s1 = sinq[s * 64 + hd];
  float c2 = cosq[s * 64 + hd + 32], s2 = sinq[s * 64 + hd + 32];
  float o1 = (v1 * c1 - v2 * s1) * 0.125f;
  float o2 = (v2 * c2 + v1 * s2) * 0.125f;
  size_t ob = ((size_t)(b * 16 + h) * 1024 + s) * 64 + hd;
  qr[ob] = (bf16_t)o1;
  qr[ob + 32] = (bf16_t)o2;
}

// ---------------------------------------------------------------------------
// Reduce split-K bf16 partials of KV proj: RoPE K -> k_r (bf16);
// V^T -> v_t (f16, [bh][hd][n]) for the f16 PV MFMA.
// ---------------------------------------------------------------------------
__global__ __launch_bounds__(256) void reduce_kv_kernel(
    const bf16_t* __restrict__ P0, const bf16_t* __restrict__ P1,
    const float* __restrict__ cosk, const float* __restrict__ sink,
    bf16_t* __restrict__ kr, f16_t* __restrict__ vt)
{
  __shared__ float ks[64][65];
  __shared__ float vs[64][65];
  int bh = blockIdx.x;
  int b = bh >> 4, h = bh & 15;
  int n0 = blockIdx.y * 64;
  int tid = threadIdx.x;
#pragma unroll
  for (int it = 0; it < 16; ++it) {
    int linear = tid + it * 256;
    int nl = linear >> 6, hd = linear & 63;
    size_t gi = ((size_t)(b * 1024 + n0 + nl)) * 2048 + h * 64 + hd;
    ks[nl][hd] = (float)P0[gi] + (float)P1[gi];
    vs[hd][nl] = (float)P0[gi + 1024] + (float)P1[gi + 1024];
  }
  __syncthreads();
#pragma unroll
  for (int it = 0; it < 16; ++it) {
    int linear = tid + it * 256;
    int nl = linear >> 6, hd = linear & 63;
    float kv = ks[nl][hd];
    float pv = ks[nl][hd ^ 32];
    float c = cosk[(n0 + nl) * 64 + hd], sn = sink[(n0 + nl) * 64 + hd];
    float o = (hd < 32) ? (kv * c - pv * sn) : (kv * c + pv * sn);
    kr[((size_t)bh * 1024 + n0 + nl) * 64 + hd] = (bf16_t)o;
    vt[((size_t)bh * 64 + nl) * 1024 + n0 + hd] = (f16_t)vs[nl][hd];
  }
}

// ---------------------------------------------------------------------------
// Barrier-free, LDS-free attention.  Swapped-operand QK^T:
//   S^T = mfma_16x16x32_bf16(A=K-frag, B=Q-frag)  -> C layout: col l15 = q,
//   row l4*4+r = k-row.  After mask+exp, P^T in registers IS the A-operand
//   layout of mfma_f32_16x16x16f16 (4 elems at k=l4*4+j), so PV runs without
//   any LDS round-trip.  V (f16, [hd][n]) gives the B-operand as contiguous
//   8 B loads.  Each wave owns 32 q-rows (2 strips); no __syncthreads.
//   grid (64 bh, 8 qtiles) x 256.
// ---------------------------------------------------------------------------
__global__ __launch_bounds__(256, 2) void attn_kernel(
    const bf16_t* __restrict__ qr, const bf16_t* __restrict__ kr,
    const f16_t* __restrict__ vt, const int* __restrict__ grp,
    bf16_t* __restrict__ outp)
{
  const int bh = blockIdx.x;
  const int b = bh >> 4, h = bh & 15;
  const int qBase = blockIdx.y * 128;
  const int tid = threadIdx.x, lane = tid & 63, w = tid >> 6;
  const int l15 = lane & 15, l4 = lane >> 4;
  const f32x4 zero = {0.f, 0.f, 0.f, 0.f};

  // Q B-fragments for this wave's 2 strips (lane l15 -> q-row)
  bf16x8 qB0[2], qB1[2];
  int gq[2];
#pragma unroll
  for (int s = 0; s < 2; ++s) {
    int qrow = qBase + w * 32 + s * 16;
    const bf16_t* qp = qr + ((size_t)bh * 1024 + qrow + l15) * 64;
    qB0[s] = *(const bf16x8*)(qp + l4 * 8);
    qB1[s] = *(const bf16x8*)(qp + 32 + l4 * 8);
    gq[s] = grp[b * 1024 + qrow + l15];
  }

  f32x4 oacc[2][4];
  float rsum[2] = {0.f, 0.f};
#pragma unroll
  for (int s = 0; s < 2; ++s)
#pragma unroll
    for (int d = 0; d < 4; ++d) oacc[s][d] = zero;

  for (int kt = 0; kt < 16; ++kt) {
    // K A-fragments (lane l15 -> k-row) + key groups
    bf16x8 kA0[4], kA1[4];
    int4 gkv[4];
#pragma unroll
    for (int nt = 0; nt < 4; ++nt) {
      const bf16_t* kp = kr + ((size_t)bh * 1024 + kt * 64 + nt * 16 + l15) * 64;
      kA0[nt] = *(const bf16x8*)(kp + l4 * 8);
      kA1[nt] = *(const bf16x8*)(kp + 32 + l4 * 8);
      gkv[nt] = *(const int4*)(grp + b * 1024 + kt * 64 + nt * 16 + l4 * 4);
    }
    // V B-fragments f16 (lane l15 -> d-col; k = l4*4+j -> n_s)
    f16x4 vf[4][4];
#pragma unroll
    for (int ntd = 0; ntd < 4; ++ntd)
#pragma unroll
      for (int ntk = 0; ntk < 4; ++ntk)
        vf[ntd][ntk] = *(const f16x4*)(
            vt + ((size_t)bh * 64 + ntd * 16 + l15) * 1024 + kt * 64 +
            ntk * 16 + l4 * 4);

#pragma unroll
    for (int s = 0; s < 2; ++s) {
      f16x4 pT[4];
      float acc = 0.f;
#pragma unroll
      for (int ntk = 0; ntk < 4; ++ntk) {
        f32x4 sacc = zero;
        sacc = __builtin_amdgcn_mfma_f32_16x16x32_bf16(kA0[ntk], qB0[s], sacc, 0, 0, 0);
        sacc = __builtin_amdgcn_mfma_f32_16x16x32_bf16(kA1[ntk], qB1[s], sacc, 0, 0, 0);
        f16x4 p;
        int gqs = gq[s];
#pragma unroll
        for (int r = 0; r < 4; ++r) {
          int gk = (r == 0) ? gkv[ntk].x : (r == 1) ? gkv[ntk].y
                   : (r == 2) ? gkv[ntk].z : gkv[ntk].w;
          float sv = sacc[r] + ((gqs == gk) ? -60.f : 0.f);
          float pe = __expf(sv);
          acc += pe;
          p[r] = (f16_t)pe;
        }
        pT[ntk] = p;
      }
      rsum[s] += acc;
#pragma unroll
      for (int ntd = 0; ntd < 4; ++ntd)
#pragma unroll
        for (int ntk = 0; ntk < 4; ++ntk)
          oacc[s][ntd] = __builtin_amdgcn_mfma_f32_16x16x16f16(
              pT[ntk], vf[ntd][ntk], oacc[s][ntd], 0, 0, 0);
    }
  }

  // Normalize: rsum holds per-lane partial for q = l15 (strip s); reduce
  // across the l4 groups, then fetch the inverse for q = l4*4+r via shuffle.
#pragma unroll
  for (int s = 0; s < 2; ++s) {
    float t = rsum[s];
    t += __shfl_xor(t, 16, 64);
    t += __shfl_xor(t, 32, 64);
    float tinv = 1.f / t;
#pragma unroll
    for (int r = 0; r < 4; ++r) {
      float inv = __shfl(tinv, l4 * 4 + r, 64);
      int srow = qBase + w * 32 + s * 16 + l4 * 4 + r;
#pragma unroll
      for (int ntd = 0; ntd < 4; ++ntd)
        outp[((size_t)(b * 1024 + srow)) * 1024 + h * 64 + ntd * 16 + l15] =
            (bf16_t)(oacc[s][ntd][r] * inv);
    }
  }
}

// ---------------------------------------------------------------------------
// Shared GEMM staging helper.
// ---------------------------------------------------------------------------
__device__ __forceinline__ void stage16(const bf16_t* gp, bf16_t* lp) {
  __builtin_amdgcn_global_load_lds(
      (__attribute__((address_space(1))) void*)gp,
      (__attribute__((address_space(3))) void*)lp, 16, 0, 0);
}

// ---------------------------------------------------------------------------
// Merged Q+KV projection GEMM, 128x128 tiles, split-K z in {0,1}.
// tileX < 8: Q; tileX >= 8: KV.  grid (24, 32, 2) = 1536 blocks.
// ---------------------------------------------------------------------------
__global__ __launch_bounds__(256, 2) void gemm_qkv(
    const bf16_t* __restrict__ qn, const bf16_t* __restrict__ WqT,
    const bf16_t* __restrict__ kvn, const bf16_t* __restrict__ WkvT,
    bf16_t* __restrict__ scr)
{
  __shared__ bf16_t sA[128 * 64];
  __shared__ bf16_t sB[128 * 64];
  const int tid = threadIdx.x;
  const int lane = tid & 63, w = tid >> 6;
  const int wr = w >> 1, wc = w & 1;
  const int z = blockIdx.z;

  const int L = blockIdx.y * 24 + blockIdx.x;
  const int xcd = L & 7, id2 = L >> 3;
  const int tileY = (xcd & 3) * 8 + (id2 % 8);
  const int tileX = (xcd >> 2) * 12 + (id2 / 8);
  const int rowBase = tileY * 128;

  const bf16_t* A;
  const bf16_t* Bt;
  bf16_t* Cb;
  int N, colBase;
  size_t zOff;
  if (tileX < 8) {
    A = qn; Bt = WqT; N = 1024; colBase = tileX * 128;
    Cb = scr; zOff = (size_t)z * 4194304;
  } else {
    A = kvn; Bt = WkvT; N = 2048; colBase = (tileX - 8) * 128;
    Cb = scr + 8388608; zOff = (size_t)z * 8388608;
  }

  const int l15 = lane & 15, l4 = lane >> 4;
  const int srow = lane >> 3;
  const int sg = lane & 7;
  const int scol = (sg ^ srow) * 8;
  const int rl = l15 & 7;
  const int g0 = (l4 ^ rl) * 8;
  const int g1 = ((4 + l4) ^ rl) * 8;

  const f32x4 zero = {0.f, 0.f, 0.f, 0.f};
  f32x4 acc[4][4];
#pragma unroll
  for (int i = 0; i < 4; ++i)
#pragma unroll
    for (int j = 0; j < 4; ++j) acc[i][j] = zero;

  const bf16_t* aBase = A + (size_t)(rowBase + w * 32 + srow) * 1024 + scol;
  const bf16_t* bBase = Bt + (size_t)(colBase + w * 32 + srow) * 1024 + scol;

  const int kStart = z * 512;
  for (int k0 = kStart; k0 < kStart + 512; k0 += 64) {
    __syncthreads();
#pragma unroll
    for (int i = 0; i < 4; ++i) {
      stage16(aBase + (size_t)i * 8 * 1024 + k0, sA + (w * 32 + i * 8) * 64);
      stage16(bBase + (size_t)i * 8 * 1024 + k0, sB + (w * 32 + i * 8) * 64);
    }
    __syncthreads();
    bf16x8 af[4], bfr[4];
#pragma unroll
    for (int mt = 0; mt < 4; ++mt)
      af[mt] = *(const bf16x8*)(sA + (wr * 64 + mt * 16 + l15) * 64 + g0);
#pragma unroll
    for (int nt = 0; nt < 4; ++nt)
      bfr[nt] = *(const bf16x8*)(sB + (wc * 64 + nt * 16 + l15) * 64 + g0);
#pragma unroll
    for (int mt = 0; mt < 4; ++mt)
#pragma unroll
      for (int nt = 0; nt < 4; ++nt)
        acc[mt][nt] = __builtin_amdgcn_mfma_f32_16x16x32_bf16(af[mt], bfr[nt],
                                                              acc[mt][nt], 0, 0, 0);
#pragma unroll
    for (int mt = 0; mt < 4; ++mt)
      af[mt] = *(const bf16x8*)(sA + (wr * 64 + mt * 16 + l15) * 64 + g1);
#pragma unroll
    for (int nt = 0; nt < 4; ++nt)
      bfr[nt] = *(const bf16x8*)(sB + (wc * 64 + nt * 16 + l15) * 64 + g1);
#pragma unroll
    for (int mt = 0; mt < 4; ++mt)
#pragma unroll
      for (int nt = 0; nt < 4; ++nt)
        acc[mt][nt] = __builtin_amdgcn_mfma_f32_16x16x32_bf16(af[mt], bfr[nt],
                                                              acc[mt][nt], 0, 0, 0);
  }

#pragma unroll
  for (int mt = 0; mt < 4; ++mt)
#pragma unroll
    for (int nt = 0; nt < 4; ++nt) {
      int col = colBase + wc * 64 + nt * 16 + l15;
#pragma unroll
      for (int r = 0; r < 4; ++r) {
        int rr = rowBase + wr * 64 + mt * 16 + l4 * 4 + r;
        Cb[zOff + (size_t)rr * N + col] = (bf16_t)acc[mt][nt][r];
      }
    }
}

// ---------------------------------------------------------------------------
// Compacted GEMM, 64x128 tile.  GATHER: A rows via idxG.
// EPI: 1 = bias+gelu->Cb, 4 = bf16 partial at z*4096*N.
// ---------------------------------------------------------------------------
template <int EPI, int GATHER>
__global__ __launch_bounds__(256, 2) void gemm64_c(
    const bf16_t* __restrict__ A, const bf16_t* __restrict__ Bt,
    int N, int Kd, int kChunk, bf16_t* __restrict__ Cb,
    const float* __restrict__ bias,
    const int* __restrict__ idxG, const int* __restrict__ McPtr)
{
  __shared__ bf16_t sA[64 * 64];
  __shared__ bf16_t sB[128 * 64];
  const int Mc = *McPtr;
  const int gx = gridDim.x;
  const int L = blockIdx.y * gx + blockIdx.x;
  const int xcd = L & 7, id2 = L >> 3;
  const int tileY = (id2 / gx) * 8 + xcd;
  const int tileX = id2 % gx;
  const int rowBase = tileY * 64;
  if (rowBase >= Mc) return;
  const int colBase = tileX * 128;

  const int tid = threadIdx.x;
  const int lane = tid & 63, w = tid >> 6;
  const int wr = w >> 1, wc = w & 1;
  const int l15 = lane & 15, l4 = lane >> 4;
  const int srow = lane >> 3;
  const int sg = lane & 7;
  const int scol = (sg ^ srow) * 8;
  const int rl = l15 & 7;
  const int g0 = (l4 ^ rl) * 8;
  const int g1 = ((4 + l4) ^ rl) * 8;

  const f32x4 zero = {0.f, 0.f, 0.f, 0.f};
  f32x4 acc[2][4];
#pragma unroll
  for (int i = 0; i < 2; ++i)
#pragma unroll
    for (int j = 0; j < 4; ++j) acc[i][j] = zero;

  const bf16_t* aB[2];
#pragma unroll
  for (int i = 0; i < 2; ++i) {
    int rowc = rowBase + w * 16 + i * 8 + srow;
    int arow = GATHER ? idxG[rowc] : rowc;
    aB[i] = A + (size_t)arow * Kd + scol;
  }
  const bf16_t* bBase = Bt + (size_t)(colBase + w * 32 + srow) * Kd + scol;

  const int kStart = blockIdx.z * kChunk;
  for (int k0 = kStart; k0 < kStart + kChunk; k0 += 64) {
    __syncthreads();
#pragma unroll
    for (int i = 0; i < 2; ++i)
      stage16(aB[i] + k0, sA + (w * 16 + i * 8) * 64);
#pragma unroll
    for (int i = 0; i < 4; ++i)
      stage16(bBase + (size_t)i * 8 * Kd + k0, sB + (w * 32 + i * 8) * 64);
    __syncthreads();
    bf16x8 af[2], bfr[4];
#pragma unroll
    for (int mt = 0; mt < 2; ++mt)
      af[mt] = *(const bf16x8*)(sA + (wr * 32 + mt * 16 + l15) * 64 + g0);
#pragma unroll
    for (int nt = 0; nt < 4; ++nt)
      bfr[nt] = *(const bf16x8*)(sB + (wc * 64 + nt * 16 + l15) * 64 + g0);
#pragma unroll
    for (int mt = 0; mt < 2; ++mt)
#pragma unroll
      for (int nt = 0; nt < 4; ++nt)
        acc[mt][nt] = __builtin_amdgcn_mfma_f32_16x16x32_bf16(af[mt], bfr[nt],
                                                              acc[mt][nt], 0, 0, 0);
#pragma unroll
    for (int mt = 0; mt < 2; ++mt)
      af[mt] = *(const bf16x8*)(sA + (wr * 32 + mt * 16 + l15) * 64 + g1);
#pragma unroll
    for (int nt = 0; nt < 4; ++nt)
      bfr[nt] = *(const bf16x8*)(sB + (wc * 64 + nt * 16 + l15) * 64 + g1);
#pragma unroll
    for (int mt = 0; mt < 2; ++mt)
#pragma unroll
      for (int nt = 0; nt < 4; ++nt)
        acc[mt][nt] = __builtin_amdgcn_mfma_f32_16x16x32_bf16(af[mt], bfr[nt],
                                                              acc[mt][nt], 0, 0, 0);
  }

  const size_t zOff = (size_t)blockIdx.z * 4096 * N;
#pragma unroll
  for (int mt = 0; mt < 2; ++mt)
#pragma unroll
    for (int nt = 0; nt < 4; ++nt) {
      int col = colBase + wc * 64 + nt * 16 + l15;
#pragma unroll
      for (int r = 0; r < 4; ++r) {
        int rr = rowBase + wr * 32 + mt * 16 + l4 * 4 + r;
        float v = acc[mt][nt][r];
        if constexpr (EPI == 1) {
          float t = v + bias[col];
          float zz = 0.7978845608028654f * (t + 0.044715f * t * t * t);
          float e = __expf(2.f * zz);
          float g = 0.5f * t * (2.f - 2.f / (e + 1.f));
          Cb[(size_t)rr * N + col] = (bf16_t)g;
        } else {
          Cb[zOff + (size_t)rr * N + col] = (bf16_t)v;
        }
      }
    }
}

// ---------------------------------------------------------------------------
// Compacted: Wo split-4 reduce + msa gate + residual -> xbuf_c, then LN2+mod.
// ---------------------------------------------------------------------------
__global__ __launch_bounds__(256) void ln2_fused_kernel(
    const bf16_t* __restrict__ P, const float* __restrict__ qx,
    const float* __restrict__ n2w, const float* __restrict__ mod,
    const int* __restrict__ idxG, const int* __restrict__ McPtr,
    float* __restrict__ xbufc, bf16_t* __restrict__ xnc)
{
  int rowc = blockIdx.x;
  if (rowc >= *McPtr) return;
  int rr = idxG[rowc];
  int b = rr >> 10;
  int tid = threadIdx.x;
  size_t rc = (size_t)rowc * 1024 + tid * 4;
  bf16x4 p0 = *(const bf16x4*)(P + rc);
  bf16x4 p1 = *(const bf16x4*)(P + 4194304 + rc);
  bf16x4 p2 = *(const bf16x4*)(P + 2 * 4194304 + rc);
  bf16x4 p3 = *(const bf16x4*)(P + 3 * 4194304 + rc);
  float4 res = ((const float4*)(qx + (size_t)rr * 1024))[tid];
  float4 g = ((const float4*)(mod + b * 6144 + 2048))[tid];
  float4 x;
  x.x = fmaf(g.x, (float)p0[0] + (float)p1[0] + (float)p2[0] + (float)p3[0], res.x);
  x.y = fmaf(g.y, (float)p0[1] + (float)p1[1] + (float)p2[1] + (float)p3[1], res.y);
  x.z = fmaf(g.z, (float)p0[2] + (float)p1[2] + (float)p2[2] + (float)p3[2], res.z);
  x.w = fmaf(g.w, (float)p0[3] + (float)p1[3] + (float)p2[3] + (float)p3[3], res.w);
  *(float4*)(xbufc + rc) = x;

  float s = x.x + x.y + x.z + x.w;
  float s2 = x.x * x.x + x.y * x.y + x.z * x.z + x.w * x.w;
#pragma unroll
  for (int off = 32; off > 0; off >>= 1) {
    s += __shfl_down(s, off, 64);
    s2 += __shfl_down(s2, off, 64);
  }
  __shared__ float ps[4], ps2[4];
  if ((tid & 63) == 0) { ps[tid >> 6] = s; ps2[tid >> 6] = s2; }
  __syncthreads();
  float mu = (ps[0] + ps[1] + ps[2] + ps[3]) * (1.0f / 1024.0f);
  float var = (ps2[0] + ps2[1] + ps2[2] + ps2[3]) * (1.0f / 1024.0f) - mu * mu;
  float rs = rsqrtf(var + 1e-5f);
  float4 sc = ((const float4*)(mod + b * 6144 + 4096))[tid];
  float4 sh = ((const float4*)(mod + b * 6144 + 3072))[tid];
  float4 wv = ((const float4*)n2w)[tid];
  float xv[4] = {x.x, x.y, x.z, x.w};
  float scv[4] = {sc.x, sc.y, sc.z, sc.w};
  float shv[4] = {sh.x, sh.y, sh.z, sh.w};
  float wvv[4] = {wv.x, wv.y, wv.z, wv.w};
#pragma unroll
  for (int i = 0; i < 4; ++i) {
    float n = (xv[i] - mu) * rs * wvv[i];
    n = n * (1.0f + scv[i]) + shv[i];
    xnc[(size_t)rowc * 1024 + tid * 4 + i] = (bf16_t)n;
  }
}

// ---------------------------------------------------------------------------
// Compacted final: W2 split-4 reduce + bias + mlp gate + residual -> out[rr]
// ---------------------------------------------------------------------------
__global__ __launch_bounds__(256) void final_reduce_kernel(
    const bf16_t* __restrict__ P, const float* __restrict__ b2,
    const float* __restrict__ mod, const int* __restrict__ idxG,
    const int* __restrict__ McPtr, const float* __restrict__ xbufc,
    float* __restrict__ out)
{
  int rowc = blockIdx.x;
  if (rowc >= *McPtr) return;
  int rr = idxG[rowc];
  int b = rr >> 10;
  int tid = threadIdx.x;
  size_t rc = (size_t)rowc * 1024 + tid * 4;
  bf16x4 p0 = *(const bf16x4*)(P + rc);
  bf16x4 p1 = *(const bf16x4*)(P + 4194304 + rc);
  bf16x4 p2 = *(const bf16x4*)(P + 2 * 4194304 + rc);
  bf16x4 p3 = *(const bf16x4*)(P + 3 * 4194304 + rc);
  float4 bb = ((const float4*)b2)[tid];
  float4 xm = *(const float4*)(xbufc + rc);
  float4 g = ((const float4*)(mod + b * 6144 + 5120))[tid];
  float v0 = (float)p0[0] + (float)p1[0] + (float)p2[0] + (float)p3[0] + bb.x;
  float v1 = (float)p0[1] + (float)p1[1] + (float)p2[1] + (float)p3[1] + bb.y;
  float v2 = (float)p0[2] + (float)p1[2] + (float)p2[2] + (float)p3[2] + bb.z;
  float v3 = (float)p0[3] + (float)p1[3] + (float)p2[3] + (float)p3[3] + bb.w;
  float4 o;
  o.x = fmaf(g.x, v0, xm.x);
  o.y = fmaf(g.y, v1, xm.y);
  o.z = fmaf(g.z, v2, xm.z);
  o.w = fmaf(g.w, v3, xm.w);
  *(float4*)(out + (size_t)rr * 1024 + tid * 4) = o;
}

// ---------------------------------------------------------------------------
extern "C" void kernel_launch(void* const* d_in, const int* in_sizes, int n_in,
                              void* d_out, int out_size, void* d_ws, size_t ws_size,
                              hipStream_t stream)
{
  const float* q_x    = (const float*)d_in[0];
  const float* kv_x   = (const float*)d_in[1];
  const float* t_cond = (const float*)d_in[2];
  const float* cos_q  = (const float*)d_in[3];
  const float* sin_q  = (const float*)d_in[4];
  const float* cos_k  = (const float*)d_in[5];
  const float* sin_k  = (const float*)d_in[6];
  const int*   grp    = (const int*)d_in[7];
  const int*   qen    = (const int*)d_in[8];
  const float* qn_w   = (const float*)d_in[9];
  const float* kvn_w  = (const float*)d_in[10];
  const float* n2_w   = (const float*)d_in[11];
  const float* Wq     = (const float*)d_in[12];
  const float* Wkv    = (const float*)d_in[13];
  const float* Wo     = (const float*)d_in[14];
  const float* W1     = (const float*)d_in[15];
  const float* b1     = (const float*)d_in[16];
  const float* W2     = (const float*)d_in[17];
  const float* b2     = (const float*)d_in[18];
  const float* adaW   = (const float*)d_in[19];
  const float* adab   = (const float*)d_in[20];
  float* out = (float*)d_out;

  char* ws = (char*)d_ws;
  const size_t MB = 1ull << 20;
  float*  mod    = (float*)(ws + 0);                   // 96 KB
  int*    idxL   = (int*)(ws + 98304);                 // 16 KB
  int*    McPtr  = (int*)(ws + 98304 + 16384);
  char*   wbase  = ws + 131072;
  bf16_t* Wq_t   = (bf16_t*)(wbase);                   // 2 MB
  bf16_t* Wkv_t  = (bf16_t*)(wbase + 2 * MB);          // 4 MB
  bf16_t* Wo_t   = (bf16_t*)(wbase + 6 * MB);          // 2 MB
  bf16_t* W1_t   = (bf16_t*)(wbase + 8 * MB);          // 8 MB
  bf16_t* W2_t   = (bf16_t*)(wbase + 16 * MB);         // 8 MB
  bf16_t* qn_mod = (bf16_t*)(wbase + 24 * MB);         // 8 MB; reused as xn_c
  bf16_t* kvn    = (bf16_t*)(wbase + 32 * MB);         // 8 MB; reused as attn_o
  bf16_t* q_r    = (bf16_t*)(wbase + 40 * MB);         // 8 MB; reused as xbuf_c
  bf16_t* k_r    = (bf16_t*)(wbase + 48 * MB);         // 8 MB
  f16_t*  v_t    = (f16_t*)(wbase + 56 * MB);          // 8 MB (f16)
  bf16_t* h1     = (bf16_t*)(wbase + 64 * MB);         // 32 MB
  bf16_t* scr    = (bf16_t*)(wbase + 96 * MB);         // 48 MB scratch
  bf16_t* xn_c   = qn_mod;
  bf16_t* attn_o = kvn;
  float*  xbuf_c = (float*)q_r;

  // 0. row compaction + disabled-row passthrough
  compact_kernel<<<1, 256, 0, stream>>>(qen, idxL, McPtr);
  copy_disabled_kernel<<<4096, 256, 0, stream>>>(qen, q_x, out);
  // 1. adaLN modulation
  mod_init_kernel<<<96, 256, 0, stream>>>(adab, mod);
  mod_partial_kernel<<<dim3(24, 8), 256, 0, stream>>>(t_cond, adaW, mod);
  // 2. weight prep
  transpose_all<<<12288, dim3(32, 8), 0, stream>>>(Wq, Wkv, Wo, W1, W2,
                                                   Wq_t, Wkv_t, Wo_t, W1_t, W2_t);
  // 3. both LayerNorms
  ln_both_kernel<<<8192, 256, 0, stream>>>(q_x, kv_x, qn_w, kvn_w, mod,
                                           qn_mod, kvn);
  // 4. merged Q+KV projection (split-2)
  gemm_qkv<<<dim3(24, 32, 2), 256, 0, stream>>>(qn_mod, Wq_t, kvn, Wkv_t, scr);
  reduce_q_rope_kernel<<<8192, 256, 0, stream>>>(scr, scr + 4194304, cos_q, sin_q, q_r);
  reduce_kv_kernel<<<dim3(64, 16), 256, 0, stream>>>(scr + 8388608, scr + 16777216,
                                                     cos_k, sin_k, k_r, v_t);
  // 5. attention: barrier-free, LDS-free (swapped-operand MFMA)
  attn_kernel<<<dim3(64, 8), 256, 0, stream>>>(q_r, k_r, v_t, grp, attn_o);
  // 6. Wo proj (compacted, gathered, split-4)
  gemm64_c<4, 1><<<dim3(8, 64, 4), 256, 0, stream>>>(attn_o, Wo_t, 1024, 1024, 256,
                                                     scr, nullptr, idxL, McPtr);
  // 7. compacted reduce + gate + residual + LN2
  ln2_fused_kernel<<<4096, 256, 0, stream>>>(scr, q_x, n2_w, mod, idxL, McPtr,
                                             xbuf_c, xn_c);
  // 8. MLP up + gelu (compacted)
  gemm64_c<1, 0><<<dim3(32, 64, 1), 256, 0, stream>>>(xn_c, W1_t, 4096, 1024, 1024,
                                                      h1, b1, idxL, McPtr);
  // 9. MLP down (compacted, split-4) + final reduce
  gemm64_c<4, 0><<<dim3(8, 64, 4), 256, 0, stream>>>(h1, W2_t, 1024, 4096, 1024,
                                                     scr, nullptr, idxL, McPtr);
  final_reduce_kernel<<<4096, 256, 0, stream>>>(scr, b2, mod, idxL, McPtr, xbuf_c, out);
}

// Round 11
// 388.390 us; speedup vs baseline: 1.1176x; 1.1176x over previous
//
#include <hip/hip_runtime.h>
#include <hip/hip_bf16.h>
#include <math.h>

typedef __bf16 bf16_t;
typedef __fp16 f16_t;
typedef __attribute__((ext_vector_type(8))) __bf16 bf16x8;
typedef __attribute__((ext_vector_type(4))) __bf16 bf16x4;
typedef __attribute__((ext_vector_type(8))) __fp16 f16x8;
typedef __attribute__((ext_vector_type(4))) __fp16 f16x4;
typedef __attribute__((ext_vector_type(4))) float f32x4;

// ---------------------------------------------------------------------------
// Row compaction: idx[0..Mc) = enabled row ids, *McPtr = Mc.
// ---------------------------------------------------------------------------
__global__ __launch_bounds__(256) void compact_kernel(
    const int* __restrict__ qen, int* __restrict__ idx, int* __restrict__ McPtr)
{
  __shared__ int cnts[256];
  int t = threadIdx.x;
  int flags[16], c = 0;
#pragma unroll
  for (int i = 0; i < 16; ++i) {
    flags[i] = qen[t * 16 + i] != 0;
    c += flags[i];
  }
  cnts[t] = c;
  __syncthreads();
  for (int off = 1; off < 256; off <<= 1) {
    int v = cnts[t];
    if (t >= off) v += cnts[t - off];
    __syncthreads();
    cnts[t] = v;
    __syncthreads();
  }
  int p = cnts[t] - c;
  int total = cnts[255];
#pragma unroll
  for (int i = 0; i < 16; ++i)
    if (flags[i]) idx[p++] = t * 16 + i;
  if (t == 0) *McPtr = total;
  for (int j = total + t; j < 4096; j += 256) idx[j] = 0;
}

// ---------------------------------------------------------------------------
// Disabled rows: out[row] = q_x[row].
// ---------------------------------------------------------------------------
__global__ __launch_bounds__(256) void copy_disabled_kernel(
    const int* __restrict__ qen, const float* __restrict__ qx,
    float* __restrict__ out)
{
  int row = blockIdx.x;
  if (qen[row]) return;
  int tid = threadIdx.x;
  ((float4*)(out + (size_t)row * 1024))[tid] =
      ((const float4*)(qx + (size_t)row * 1024))[tid];
}

// ---------------------------------------------------------------------------
// mod init + partial (split-K atomics)
// ---------------------------------------------------------------------------
__global__ __launch_bounds__(256) void mod_init_kernel(
    const float* __restrict__ adab, float* __restrict__ mod)
{
  int i = blockIdx.x * 256 + threadIdx.x;
  mod[i] = adab[i % 6144];
}

__global__ __launch_bounds__(256) void mod_partial_kernel(
    const float* __restrict__ tc, const float* __restrict__ adaW,
    float* __restrict__ mod)
{
  __shared__ float st[4][128];
  int tid = threadIdx.x, z = blockIdx.y;
  for (int i = tid; i < 512; i += 256)
    st[i >> 7][i & 127] = tc[(i >> 7) * 1024 + z * 128 + (i & 127)];
  __syncthreads();
  int col = blockIdx.x * 256 + tid;
  float a0 = 0.f, a1 = 0.f, a2 = 0.f, a3 = 0.f;
  for (int k = 0; k < 128; ++k) {
    float wv = adaW[(size_t)(z * 128 + k) * 6144 + col];
    a0 = fmaf(st[0][k], wv, a0);
    a1 = fmaf(st[1][k], wv, a1);
    a2 = fmaf(st[2][k], wv, a2);
    a3 = fmaf(st[3][k], wv, a3);
  }
  atomicAdd(&mod[col], a0);
  atomicAdd(&mod[6144 + col], a1);
  atomicAdd(&mod[2 * 6144 + col], a2);
  atomicAdd(&mod[3 * 6144 + col], a3);
}

// ---------------------------------------------------------------------------
// All five weight transposes (f32 -> bf16) in one launch.
// ---------------------------------------------------------------------------
__global__ __launch_bounds__(256) void transpose_all(
    const float* __restrict__ Wq, const float* __restrict__ Wkv,
    const float* __restrict__ Wo, const float* __restrict__ W1,
    const float* __restrict__ W2,
    bf16_t* __restrict__ oWq, bf16_t* __restrict__ oWkv,
    bf16_t* __restrict__ oWo, bf16_t* __restrict__ oW1,
    bf16_t* __restrict__ oW2)
{
  __shared__ float tile[32][33];
  int bid = blockIdx.x;
  const float* in; bf16_t* out; int R, C, gx, local;
  if (bid < 1024)      { in = Wq;  out = oWq;  R = 1024; C = 1024; gx = 32;  local = bid; }
  else if (bid < 3072) { in = Wkv; out = oWkv; R = 1024; C = 2048; gx = 64;  local = bid - 1024; }
  else if (bid < 4096) { in = Wo;  out = oWo;  R = 1024; C = 1024; gx = 32;  local = bid - 3072; }
  else if (bid < 8192) { in = W1;  out = oW1;  R = 1024; C = 4096; gx = 128; local = bid - 4096; }
  else                 { in = W2;  out = oW2;  R = 4096; C = 1024; gx = 32;  local = bid - 8192; }
  int c0 = (local % gx) * 32, r0 = (local / gx) * 32;
  int tx = threadIdx.x, ty = threadIdx.y;
#pragma unroll
  for (int i = 0; i < 4; ++i)
    tile[ty + i * 8][tx] = in[(size_t)(r0 + ty + i * 8) * C + c0 + tx];
  __syncthreads();
#pragma unroll
  for (int i = 0; i < 4; ++i)
    out[(size_t)(c0 + ty + i * 8) * R + r0 + tx] = (bf16_t)tile[tx][ty + i * 8];
}

// ---------------------------------------------------------------------------
// Both input LayerNorms in one launch.
// ---------------------------------------------------------------------------
__global__ __launch_bounds__(256) void ln_both_kernel(
    const float* __restrict__ qx, const float* __restrict__ kvx,
    const float* __restrict__ qnw, const float* __restrict__ kvnw,
    const float* __restrict__ mod,
    bf16_t* __restrict__ qn_out, bf16_t* __restrict__ kvn_out)
{
  int rowg = blockIdx.x;
  bool isQ = rowg < 4096;
  int row = isQ ? rowg : rowg - 4096;
  int b = row >> 10;
  int tid = threadIdx.x;
  const float* x = (isQ ? qx : kvx) + (size_t)row * 1024;
  const float* wgt = isQ ? qnw : kvnw;
  bf16_t* outp = (isQ ? qn_out : kvn_out) + (size_t)row * 1024;

  float4 v = ((const float4*)x)[tid];
  float s = v.x + v.y + v.z + v.w;
  float s2 = v.x * v.x + v.y * v.y + v.z * v.z + v.w * v.w;
#pragma unroll
  for (int off = 32; off > 0; off >>= 1) {
    s += __shfl_down(s, off, 64);
    s2 += __shfl_down(s2, off, 64);
  }
  __shared__ float ps[4], ps2[4];
  if ((tid & 63) == 0) { ps[tid >> 6] = s; ps2[tid >> 6] = s2; }
  __syncthreads();
  float mu = (ps[0] + ps[1] + ps[2] + ps[3]) * (1.0f / 1024.0f);
  float var = (ps2[0] + ps2[1] + ps2[2] + ps2[3]) * (1.0f / 1024.0f) - mu * mu;
  float rs = rsqrtf(var + 1e-5f);
  float xv[4] = {v.x, v.y, v.z, v.w};
#pragma unroll
  for (int i = 0; i < 4; ++i) {
    int col = tid * 4 + i;
    float n = (xv[i] - mu) * rs * wgt[col];
    if (isQ)
      n = n * (1.0f + mod[b * 6144 + 1024 + col]) + mod[b * 6144 + col];
    outp[col] = (bf16_t)n;
  }
}

// ---------------------------------------------------------------------------
// Reduce split-K bf16 partials of Q proj + RoPE + scale -> q_r (B,H,S,64)
// ---------------------------------------------------------------------------
__global__ __launch_bounds__(256) void reduce_q_rope_kernel(
    const bf16_t* __restrict__ P0, const bf16_t* __restrict__ P1,
    const float* __restrict__ cosq, const float* __restrict__ sinq,
    bf16_t* __restrict__ qr)
{
  int t = blockIdx.x * 256 + threadIdx.x;
  int hd = t & 31;
  int h = (t >> 5) & 15;
  int s = (t >> 9) & 1023;
  int b = t >> 19;
  size_t base = ((size_t)(b * 1024 + s)) * 1024 + h * 64 + hd;
  float v1 = (float)P0[base] + (float)P1[base];
  float v2 = (float)P0[base + 32] + (float)P1[base + 32];
  float c1 = cosq[s * 64 + hd], s1 = sinq[s * 64 + hd];
  float c2 = cosq[s * 64 + hd + 32], s2 = sinq[s * 64 + hd + 32];
  float o1 = (v1 * c1 - v2 * s1) * 0.125f;
  float o2 = (v2 * c2 + v1 * s2) * 0.125f;
  size_t ob = ((size_t)(b * 16 + h) * 1024 + s) * 64 + hd;
  qr[ob] = (bf16_t)o1;
  qr[ob + 32] = (bf16_t)o2;
}

// ---------------------------------------------------------------------------
// Reduce split-K bf16 partials of KV proj: RoPE K -> k_r (bf16);
// V^T -> v_t (f16, [bh][hd][n]) for the f16 PV MFMA.
// ---------------------------------------------------------------------------
__global__ __launch_bounds__(256) void reduce_kv_kernel(
    const bf16_t* __restrict__ P0, const bf16_t* __restrict__ P1,
    const float* __restrict__ cosk, const float* __restrict__ sink,
    bf16_t* __restrict__ kr, f16_t* __restrict__ vt)
{
  __shared__ float ks[64][65];
  __shared__ float vs[64][65];
  int bh = blockIdx.x;
  int b = bh >> 4, h = bh & 15;
  int n0 = blockIdx.y * 64;
  int tid = threadIdx.x;
#pragma unroll
  for (int it = 0; it < 16; ++it) {
    int linear = tid + it * 256;
    int nl = linear >> 6, hd = linear & 63;
    size_t gi = ((size_t)(b * 1024 + n0 + nl)) * 2048 + h * 64 + hd;
    ks[nl][hd] = (float)P0[gi] + (float)P1[gi];
    vs[hd][nl] = (float)P0[gi + 1024] + (float)P1[gi + 1024];
  }
  __syncthreads();
#pragma unroll
  for (int it = 0; it < 16; ++it) {
    int linear = tid + it * 256;
    int nl = linear >> 6, hd = linear & 63;
    float kv = ks[nl][hd];
    float pv = ks[nl][hd ^ 32];
    float c = cosk[(n0 + nl) * 64 + hd], sn = sink[(n0 + nl) * 64 + hd];
    float o = (hd < 32) ? (kv * c - pv * sn) : (kv * c + pv * sn);
    kr[((size_t)bh * 1024 + n0 + nl) * 64 + hd] = (bf16_t)o;
    vt[((size_t)bh * 64 + nl) * 1024 + n0 + hd] = (f16_t)vs[nl][hd];
  }
}

// ---------------------------------------------------------------------------
// Hybrid attention: LDS-staged K/V (shared by 4 waves, 2 barriers/k-tile,
// as in the 42.6 us round-6 kernel) + register-resident P via swapped-operand
// MFMA (round-10-verified layouts):
//   S^T = mfma_16x16x32_bf16(A=K-frag, B=Q-frag): C col l15 = q,
//   row l4*4+r = key.  After mask+exp, P^T in regs IS the A-operand of
//   mfma_f32_16x16x16f16 (k = l4*4+j), so PV needs no LDS round-trip.
//   V (f16, [hd][n]) staged to LDS; B-operand reads are 8 B contiguous.
// 128-row Q tile; wave w owns rows [32w,32w+32) as 2 strips.  grid (64,8).
// ---------------------------------------------------------------------------
__global__ __launch_bounds__(256, 2) void attn_kernel(
    const bf16_t* __restrict__ qr, const bf16_t* __restrict__ kr,
    const f16_t* __restrict__ vt, const int* __restrict__ grp,
    bf16_t* __restrict__ outp)
{
  __shared__ bf16_t Ks[64 * 68];
  __shared__ f16_t Vs[64 * 68];
  const int bh = blockIdx.x;
  const int b = bh >> 4, h = bh & 15;
  const int qBase = blockIdx.y * 128;
  const int tid = threadIdx.x, lane = tid & 63, w = tid >> 6;
  const int l15 = lane & 15, l4 = lane >> 4;
  const f32x4 zero = {0.f, 0.f, 0.f, 0.f};

  // Q B-fragments for this wave's 2 strips (lane l15 -> q-row)
  bf16x8 qB0[2], qB1[2];
  int gq[2];
#pragma unroll
  for (int s = 0; s < 2; ++s) {
    int qrow = qBase + w * 32 + s * 16;
    const bf16_t* qp = qr + ((size_t)bh * 1024 + qrow + l15) * 64;
    qB0[s] = *(const bf16x8*)(qp + l4 * 8);
    qB1[s] = *(const bf16x8*)(qp + 32 + l4 * 8);
    gq[s] = grp[b * 1024 + qrow + l15];
  }

  f32x4 oacc[2][4];
  float rsum[2] = {0.f, 0.f};
#pragma unroll
  for (int s = 0; s < 2; ++s)
#pragma unroll
    for (int d = 0; d < 4; ++d) oacc[s][d] = zero;

  for (int kt = 0; kt < 16; ++kt) {
    __syncthreads();
#pragma unroll
    for (int i = 0; i < 2; ++i) {
      int c = tid * 2 + i;
      int r = c >> 3, cc = (c & 7) * 8;
      *(bf16x8*)(Ks + r * 68 + cc) =
          *(const bf16x8*)(kr + ((size_t)bh * 1024 + kt * 64 + r) * 64 + cc);
      *(f16x8*)(Vs + r * 68 + cc) =
          *(const f16x8*)(vt + ((size_t)bh * 64 + r) * 1024 + kt * 64 + cc);
    }
    __syncthreads();

    // K A-fragments from LDS (lane l15 -> key-row) + key groups (per-lane)
    bf16x8 kA0[4], kA1[4];
    int4 gkv[4];
#pragma unroll
    for (int ntk = 0; ntk < 4; ++ntk) {
      kA0[ntk] = *(const bf16x8*)(Ks + (ntk * 16 + l15) * 68 + l4 * 8);
      kA1[ntk] = *(const bf16x8*)(Ks + (ntk * 16 + l15) * 68 + 32 + l4 * 8);
      gkv[ntk] = *(const int4*)(grp + b * 1024 + kt * 64 + ntk * 16 + l4 * 4);
    }
    // V B-fragments from LDS (lane l15 -> d-col; k = l4*4+j -> key)
    f16x4 vf[4][4];
#pragma unroll
    for (int ntd = 0; ntd < 4; ++ntd)
#pragma unroll
      for (int ntk = 0; ntk < 4; ++ntk)
        vf[ntd][ntk] = *(const f16x4*)(Vs + (ntd * 16 + l15) * 68 +
                                       ntk * 16 + l4 * 4);

#pragma unroll
    for (int s = 0; s < 2; ++s) {
      f16x4 pT[4];
      float acc = 0.f;
      int gqs = gq[s];
#pragma unroll
      for (int ntk = 0; ntk < 4; ++ntk) {
        f32x4 sacc = zero;
        sacc = __builtin_amdgcn_mfma_f32_16x16x32_bf16(kA0[ntk], qB0[s], sacc, 0, 0, 0);
        sacc = __builtin_amdgcn_mfma_f32_16x16x32_bf16(kA1[ntk], qB1[s], sacc, 0, 0, 0);
        f16x4 p;
#pragma unroll
        for (int r = 0; r < 4; ++r) {
          int gk = (r == 0) ? gkv[ntk].x : (r == 1) ? gkv[ntk].y
                   : (r == 2) ? gkv[ntk].z : gkv[ntk].w;
          float sv = sacc[r] + ((gqs == gk) ? -60.f : 0.f);
          float pe = __expf(sv);
          acc += pe;
          p[r] = (f16_t)pe;
        }
        pT[ntk] = p;
      }
      rsum[s] += acc;
#pragma unroll
      for (int ntd = 0; ntd < 4; ++ntd)
#pragma unroll
        for (int ntk = 0; ntk < 4; ++ntk)
          oacc[s][ntd] = __builtin_amdgcn_mfma_f32_16x16x16f16(
              pT[ntk], vf[ntd][ntk], oacc[s][ntd], 0, 0, 0);
    }
  }

  // Normalize: rsum per-lane holds partial for q = l15 (strip s); reduce
  // across l4 groups, then fetch inverse for q = l4*4+r via shuffle.
#pragma unroll
  for (int s = 0; s < 2; ++s) {
    float t = rsum[s];
    t += __shfl_xor(t, 16, 64);
    t += __shfl_xor(t, 32, 64);
    float tinv = 1.f / t;
#pragma unroll
    for (int r = 0; r < 4; ++r) {
      float inv = __shfl(tinv, l4 * 4 + r, 64);
      int srow = qBase + w * 32 + s * 16 + l4 * 4 + r;
#pragma unroll
      for (int ntd = 0; ntd < 4; ++ntd)
        outp[((size_t)(b * 1024 + srow)) * 1024 + h * 64 + ntd * 16 + l15] =
            (bf16_t)(oacc[s][ntd][r] * inv);
    }
  }
}

// ---------------------------------------------------------------------------
// Shared GEMM staging helper.
// ---------------------------------------------------------------------------
__device__ __forceinline__ void stage16(const bf16_t* gp, bf16_t* lp) {
  __builtin_amdgcn_global_load_lds(
      (__attribute__((address_space(1))) void*)gp,
      (__attribute__((address_space(3))) void*)lp, 16, 0, 0);
}

// ---------------------------------------------------------------------------
// Merged Q+KV projection GEMM, 128x128 tiles, split-K z in {0,1}.
// tileX < 8: Q; tileX >= 8: KV.  grid (24, 32, 2) = 1536 blocks.
// ---------------------------------------------------------------------------
__global__ __launch_bounds__(256, 2) void gemm_qkv(
    const bf16_t* __restrict__ qn, const bf16_t* __restrict__ WqT,
    const bf16_t* __restrict__ kvn, const bf16_t* __restrict__ WkvT,
    bf16_t* __restrict__ scr)
{
  __shared__ bf16_t sA[128 * 64];
  __shared__ bf16_t sB[128 * 64];
  const int tid = threadIdx.x;
  const int lane = tid & 63, w = tid >> 6;
  const int wr = w >> 1, wc = w & 1;
  const int z = blockIdx.z;

  const int L = blockIdx.y * 24 + blockIdx.x;
  const int xcd = L & 7, id2 = L >> 3;
  const int tileY = (xcd & 3) * 8 + (id2 % 8);
  const int tileX = (xcd >> 2) * 12 + (id2 / 8);
  const int rowBase = tileY * 128;

  const bf16_t* A;
  const bf16_t* Bt;
  bf16_t* Cb;
  int N, colBase;
  size_t zOff;
  if (tileX < 8) {
    A = qn; Bt = WqT; N = 1024; colBase = tileX * 128;
    Cb = scr; zOff = (size_t)z * 4194304;
  } else {
    A = kvn; Bt = WkvT; N = 2048; colBase = (tileX - 8) * 128;
    Cb = scr + 8388608; zOff = (size_t)z * 8388608;
  }

  const int l15 = lane & 15, l4 = lane >> 4;
  const int srow = lane >> 3;
  const int sg = lane & 7;
  const int scol = (sg ^ srow) * 8;
  const int rl = l15 & 7;
  const int g0 = (l4 ^ rl) * 8;
  const int g1 = ((4 + l4) ^ rl) * 8;

  const f32x4 zero = {0.f, 0.f, 0.f, 0.f};
  f32x4 acc[4][4];
#pragma unroll
  for (int i = 0; i < 4; ++i)
#pragma unroll
    for (int j = 0; j < 4; ++j) acc[i][j] = zero;

  const bf16_t* aBase = A + (size_t)(rowBase + w * 32 + srow) * 1024 + scol;
  const bf16_t* bBase = Bt + (size_t)(colBase + w * 32 + srow) * 1024 + scol;

  const int kStart = z * 512;
  for (int k0 = kStart; k0 < kStart + 512; k0 += 64) {
    __syncthreads();
#pragma unroll
    for (int i = 0; i < 4; ++i) {
      stage16(aBase + (size_t)i * 8 * 1024 + k0, sA + (w * 32 + i * 8) * 64);
      stage16(bBase + (size_t)i * 8 * 1024 + k0, sB + (w * 32 + i * 8) * 64);
    }
    __syncthreads();
    bf16x8 af[4], bfr[4];
#pragma unroll
    for (int mt = 0; mt < 4; ++mt)
      af[mt] = *(const bf16x8*)(sA + (wr * 64 + mt * 16 + l15) * 64 + g0);
#pragma unroll
    for (int nt = 0; nt < 4; ++nt)
      bfr[nt] = *(const bf16x8*)(sB + (wc * 64 + nt * 16 + l15) * 64 + g0);
#pragma unroll
    for (int mt = 0; mt < 4; ++mt)
#pragma unroll
      for (int nt = 0; nt < 4; ++nt)
        acc[mt][nt] = __builtin_amdgcn_mfma_f32_16x16x32_bf16(af[mt], bfr[nt],
                                                              acc[mt][nt], 0, 0, 0);
#pragma unroll
    for (int mt = 0; mt < 4; ++mt)
      af[mt] = *(const bf16x8*)(sA + (wr * 64 + mt * 16 + l15) * 64 + g1);
#pragma unroll
    for (int nt = 0; nt < 4; ++nt)
      bfr[nt] = *(const bf16x8*)(sB + (wc * 64 + nt * 16 + l15) * 64 + g1);
#pragma unroll
    for (int mt = 0; mt < 4; ++mt)
#pragma unroll
      for (int nt = 0; nt < 4; ++nt)
        acc[mt][nt] = __builtin_amdgcn_mfma_f32_16x16x32_bf16(af[mt], bfr[nt],
                                                              acc[mt][nt], 0, 0, 0);
  }

#pragma unroll
  for (int mt = 0; mt < 4; ++mt)
#pragma unroll
    for (int nt = 0; nt < 4; ++nt) {
      int col = colBase + wc * 64 + nt * 16 + l15;
#pragma unroll
      for (int r = 0; r < 4; ++r) {
        int rr = rowBase + wr * 64 + mt * 16 + l4 * 4 + r;
        Cb[zOff + (size_t)rr * N + col] = (bf16_t)acc[mt][nt][r];
      }
    }
}

// ---------------------------------------------------------------------------
// Compacted GEMM, 64x128 tile.  GATHER: A rows via idxG.
// EPI: 1 = bias+gelu->Cb, 4 = bf16 partial at z*4096*N.
// ---------------------------------------------------------------------------
template <int EPI, int GATHER>
__global__ __launch_bounds__(256, 2) void gemm64_c(
    const bf16_t* __restrict__ A, const bf16_t* __restrict__ Bt,
    int N, int Kd, int kChunk, bf16_t* __restrict__ Cb,
    const float* __restrict__ bias,
    const int* __restrict__ idxG, const int* __restrict__ McPtr)
{
  __shared__ bf16_t sA[64 * 64];
  __shared__ bf16_t sB[128 * 64];
  const int Mc = *McPtr;
  const int gx = gridDim.x;
  const int L = blockIdx.y * gx + blockIdx.x;
  const int xcd = L & 7, id2 = L >> 3;
  const int tileY = (id2 / gx) * 8 + xcd;
  const int tileX = id2 % gx;
  const int rowBase = tileY * 64;
  if (rowBase >= Mc) return;
  const int colBase = tileX * 128;

  const int tid = threadIdx.x;
  const int lane = tid & 63, w = tid >> 6;
  const int wr = w >> 1, wc = w & 1;
  const int l15 = lane & 15, l4 = lane >> 4;
  const int srow = lane >> 3;
  const int sg = lane & 7;
  const int scol = (sg ^ srow) * 8;
  const int rl = l15 & 7;
  const int g0 = (l4 ^ rl) * 8;
  const int g1 = ((4 + l4) ^ rl) * 8;

  const f32x4 zero = {0.f, 0.f, 0.f, 0.f};
  f32x4 acc[2][4];
#pragma unroll
  for (int i = 0; i < 2; ++i)
#pragma unroll
    for (int j = 0; j < 4; ++j) acc[i][j] = zero;

  const bf16_t* aB[2];
#pragma unroll
  for (int i = 0; i < 2; ++i) {
    int rowc = rowBase + w * 16 + i * 8 + srow;
    int arow = GATHER ? idxG[rowc] : rowc;
    aB[i] = A + (size_t)arow * Kd + scol;
  }
  const bf16_t* bBase = Bt + (size_t)(colBase + w * 32 + srow) * Kd + scol;

  const int kStart = blockIdx.z * kChunk;
  for (int k0 = kStart; k0 < kStart + kChunk; k0 += 64) {
    __syncthreads();
#pragma unroll
    for (int i = 0; i < 2; ++i)
      stage16(aB[i] + k0, sA + (w * 16 + i * 8) * 64);
#pragma unroll
    for (int i = 0; i < 4; ++i)
      stage16(bBase + (size_t)i * 8 * Kd + k0, sB + (w * 32 + i * 8) * 64);
    __syncthreads();
    bf16x8 af[2], bfr[4];
#pragma unroll
    for (int mt = 0; mt < 2; ++mt)
      af[mt] = *(const bf16x8*)(sA + (wr * 32 + mt * 16 + l15) * 64 + g0);
#pragma unroll
    for (int nt = 0; nt < 4; ++nt)
      bfr[nt] = *(const bf16x8*)(sB + (wc * 64 + nt * 16 + l15) * 64 + g0);
#pragma unroll
    for (int mt = 0; mt < 2; ++mt)
#pragma unroll
      for (int nt = 0; nt < 4; ++nt)
        acc[mt][nt] = __builtin_amdgcn_mfma_f32_16x16x32_bf16(af[mt], bfr[nt],
                                                              acc[mt][nt], 0, 0, 0);
#pragma unroll
    for (int mt = 0; mt < 2; ++mt)
      af[mt] = *(const bf16x8*)(sA + (wr * 32 + mt * 16 + l15) * 64 + g1);
#pragma unroll
    for (int nt = 0; nt < 4; ++nt)
      bfr[nt] = *(const bf16x8*)(sB + (wc * 64 + nt * 16 + l15) * 64 + g1);
#pragma unroll
    for (int mt = 0; mt < 2; ++mt)
#pragma unroll
      for (int nt = 0; nt < 4; ++nt)
        acc[mt][nt] = __builtin_amdgcn_mfma_f32_16x16x32_bf16(af[mt], bfr[nt],
                                                              acc[mt][nt], 0, 0, 0);
  }

  const size_t zOff = (size_t)blockIdx.z * 4096 * N;
#pragma unroll
  for (int mt = 0; mt < 2; ++mt)
#pragma unroll
    for (int nt = 0; nt < 4; ++nt) {
      int col = colBase + wc * 64 + nt * 16 + l15;
#pragma unroll
      for (int r = 0; r < 4; ++r) {
        int rr = rowBase + wr * 32 + mt * 16 + l4 * 4 + r;
        float v = acc[mt][nt][r];
        if constexpr (EPI == 1) {
          float t = v + bias[col];
          float zz = 0.7978845608028654f * (t + 0.044715f * t * t * t);
          float e = __expf(2.f * zz);
          float g = 0.5f * t * (2.f - 2.f / (e + 1.f));
          Cb[(size_t)rr * N + col] = (bf16_t)g;
        } else {
          Cb[zOff + (size_t)rr * N + col] = (bf16_t)v;
        }
      }
    }
}

// ---------------------------------------------------------------------------
// Compacted: Wo split-4 reduce + msa gate + residual -> xbuf_c, then LN2+mod.
// ---------------------------------------------------------------------------
__global__ __launch_bounds__(256) void ln2_fused_kernel(
    const bf16_t* __restrict__ P, const float* __restrict__ qx,
    const float* __restrict__ n2w, const float* __restrict__ mod,
    const int* __restrict__ idxG, const int* __restrict__ McPtr,
    float* __restrict__ xbufc, bf16_t* __restrict__ xnc)
{
  int rowc = blockIdx.x;
  if (rowc >= *McPtr) return;
  int rr = idxG[rowc];
  int b = rr >> 10;
  int tid = threadIdx.x;
  size_t rc = (size_t)rowc * 1024 + tid * 4;
  bf16x4 p0 = *(const bf16x4*)(P + rc);
  bf16x4 p1 = *(const bf16x4*)(P + 4194304 + rc);
  bf16x4 p2 = *(const bf16x4*)(P + 2 * 4194304 + rc);
  bf16x4 p3 = *(const bf16x4*)(P + 3 * 4194304 + rc);
  float4 res = ((const float4*)(qx + (size_t)rr * 1024))[tid];
  float4 g = ((const float4*)(mod + b * 6144 + 2048))[tid];
  float4 x;
  x.x = fmaf(g.x, (float)p0[0] + (float)p1[0] + (float)p2[0] + (float)p3[0], res.x);
  x.y = fmaf(g.y, (float)p0[1] + (float)p1[1] + (float)p2[1] + (float)p3[1], res.y);
  x.z = fmaf(g.z, (float)p0[2] + (float)p1[2] + (float)p2[2] + (float)p3[2], res.z);
  x.w = fmaf(g.w, (float)p0[3] + (float)p1[3] + (float)p2[3] + (float)p3[3], res.w);
  *(float4*)(xbufc + rc) = x;

  float s = x.x + x.y + x.z + x.w;
  float s2 = x.x * x.x + x.y * x.y + x.z * x.z + x.w * x.w;
#pragma unroll
  for (int off = 32; off > 0; off >>= 1) {
    s += __shfl_down(s, off, 64);
    s2 += __shfl_down(s2, off, 64);
  }
  __shared__ float ps[4], ps2[4];
  if ((tid & 63) == 0) { ps[tid >> 6] = s; ps2[tid >> 6] = s2; }
  __syncthreads();
  float mu = (ps[0] + ps[1] + ps[2] + ps[3]) * (1.0f / 1024.0f);
  float var = (ps2[0] + ps2[1] + ps2[2] + ps2[3]) * (1.0f / 1024.0f) - mu * mu;
  float rs = rsqrtf(var + 1e-5f);
  float4 sc = ((const float4*)(mod + b * 6144 + 4096))[tid];
  float4 sh = ((const float4*)(mod + b * 6144 + 3072))[tid];
  float4 wv = ((const float4*)n2w)[tid];
  float xv[4] = {x.x, x.y, x.z, x.w};
  float scv[4] = {sc.x, sc.y, sc.z, sc.w};
  float shv[4] = {sh.x, sh.y, sh.z, sh.w};
  float wvv[4] = {wv.x, wv.y, wv.z, wv.w};
#pragma unroll
  for (int i = 0; i < 4; ++i) {
    float n = (xv[i] - mu) * rs * wvv[i];
    n = n * (1.0f + scv[i]) + shv[i];
    xnc[(size_t)rowc * 1024 + tid * 4 + i] = (bf16_t)n;
  }
}

// ---------------------------------------------------------------------------
// Compacted final: W2 split-4 reduce + bias + mlp gate + residual -> out[rr]
// ---------------------------------------------------------------------------
__global__ __launch_bounds__(256) void final_reduce_kernel(
    const bf16_t* __restrict__ P, const float* __restrict__ b2,
    const float* __restrict__ mod, const int* __restrict__ idxG,
    const int* __restrict__ McPtr, const float* __restrict__ xbufc,
    float* __restrict__ out)
{
  int rowc = blockIdx.x;
  if (rowc >= *McPtr) return;
  int rr = idxG[rowc];
  int b = rr >> 10;
  int tid = threadIdx.x;
  size_t rc = (size_t)rowc * 1024 + tid * 4;
  bf16x4 p0 = *(const bf16x4*)(P + rc);
  bf16x4 p1 = *(const bf16x4*)(P + 4194304 + rc);
  bf16x4 p2 = *(const bf16x4*)(P + 2 * 4194304 + rc);
  bf16x4 p3 = *(const bf16x4*)(P + 3 * 4194304 + rc);
  float4 bb = ((const float4*)b2)[tid];
  float4 xm = *(const float4*)(xbufc + rc);
  float4 g = ((const float4*)(mod + b * 6144 + 5120))[tid];
  float v0 = (float)p0[0] + (float)p1[0] + (float)p2[0] + (float)p3[0] + bb.x;
  float v1 = (float)p0[1] + (float)p1[1] + (float)p2[1] + (float)p3[1] + bb.y;
  float v2 = (float)p0[2] + (float)p1[2] + (float)p2[2] + (float)p3[2] + bb.z;
  float v3 = (float)p0[3] + (float)p1[3] + (float)p2[3] + (float)p3[3] + bb.w;
  float4 o;
  o.x = fmaf(g.x, v0, xm.x);
  o.y = fmaf(g.y, v1, xm.y);
  o.z = fmaf(g.z, v2, xm.z);
  o.w = fmaf(g.w, v3, xm.w);
  *(float4*)(out + (size_t)rr * 1024 + tid * 4) = o;
}

// ---------------------------------------------------------------------------
extern "C" void kernel_launch(void* const* d_in, const int* in_sizes, int n_in,
                              void* d_out, int out_size, void* d_ws, size_t ws_size,
                              hipStream_t stream)
{
  const float* q_x    = (const float*)d_in[0];
  const float* kv_x   = (const float*)d_in[1];
  const float* t_cond = (const float*)d_in[2];
  const float* cos_q  = (const float*)d_in[3];
  const float* sin_q  = (const float*)d_in[4];
  const float* cos_k  = (const float*)d_in[5];
  const float* sin_k  = (const float*)d_in[6];
  const int*   grp    = (const int*)d_in[7];
  const int*   qen    = (const int*)d_in[8];
  const float* qn_w   = (const float*)d_in[9];
  const float* kvn_w  = (const float*)d_in[10];
  const float* n2_w   = (const float*)d_in[11];
  const float* Wq     = (const float*)d_in[12];
  const float* Wkv    = (const float*)d_in[13];
  const float* Wo     = (const float*)d_in[14];
  const float* W1     = (const float*)d_in[15];
  const float* b1     = (const float*)d_in[16];
  const float* W2     = (const float*)d_in[17];
  const float* b2     = (const float*)d_in[18];
  const float* adaW   = (const float*)d_in[19];
  const float* adab   = (const float*)d_in[20];
  float* out = (float*)d_out;

  char* ws = (char*)d_ws;
  const size_t MB = 1ull << 20;
  float*  mod    = (float*)(ws + 0);                   // 96 KB
  int*    idxL   = (int*)(ws + 98304);                 // 16 KB
  int*    McPtr  = (int*)(ws + 98304 + 16384);
  char*   wbase  = ws + 131072;
  bf16_t* Wq_t   = (bf16_t*)(wbase);                   // 2 MB
  bf16_t* Wkv_t  = (bf16_t*)(wbase + 2 * MB);          // 4 MB
  bf16_t* Wo_t   = (bf16_t*)(wbase + 6 * MB);          // 2 MB
  bf16_t* W1_t   = (bf16_t*)(wbase + 8 * MB);          // 8 MB
  bf16_t* W2_t   = (bf16_t*)(wbase + 16 * MB);         // 8 MB
  bf16_t* qn_mod = (bf16_t*)(wbase + 24 * MB);         // 8 MB; reused as xn_c
  bf16_t* kvn    = (bf16_t*)(wbase + 32 * MB);         // 8 MB; reused as attn_o
  bf16_t* q_r    = (bf16_t*)(wbase + 40 * MB);         // 8 MB; reused as xbuf_c
  bf16_t* k_r    = (bf16_t*)(wbase + 48 * MB);         // 8 MB
  f16_t*  v_t    = (f16_t*)(wbase + 56 * MB);          // 8 MB (f16)
  bf16_t* h1     = (bf16_t*)(wbase + 64 * MB);         // 32 MB
  bf16_t* scr    = (bf16_t*)(wbase + 96 * MB);         // 48 MB scratch
  bf16_t* xn_c   = qn_mod;
  bf16_t* attn_o = kvn;
  float*  xbuf_c = (float*)q_r;

  // 0. row compaction + disabled-row passthrough
  compact_kernel<<<1, 256, 0, stream>>>(qen, idxL, McPtr);
  copy_disabled_kernel<<<4096, 256, 0, stream>>>(qen, q_x, out);
  // 1. adaLN modulation
  mod_init_kernel<<<96, 256, 0, stream>>>(adab, mod);
  mod_partial_kernel<<<dim3(24, 8), 256, 0, stream>>>(t_cond, adaW, mod);
  // 2. weight prep
  transpose_all<<<12288, dim3(32, 8), 0, stream>>>(Wq, Wkv, Wo, W1, W2,
                                                   Wq_t, Wkv_t, Wo_t, W1_t, W2_t);
  // 3. both LayerNorms
  ln_both_kernel<<<8192, 256, 0, stream>>>(q_x, kv_x, qn_w, kvn_w, mod,
                                           qn_mod, kvn);
  // 4. merged Q+KV projection (split-2)
  gemm_qkv<<<dim3(24, 32, 2), 256, 0, stream>>>(qn_mod, Wq_t, kvn, Wkv_t, scr);
  reduce_q_rope_kernel<<<8192, 256, 0, stream>>>(scr, scr + 4194304, cos_q, sin_q, q_r);
  reduce_kv_kernel<<<dim3(64, 16), 256, 0, stream>>>(scr + 8388608, scr + 16777216,
                                                     cos_k, sin_k, k_r, v_t);
  // 5. attention: hybrid (LDS K/V staging + register-resident P)
  attn_kernel<<<dim3(64, 8), 256, 0, stream>>>(q_r, k_r, v_t, grp, attn_o);
  // 6. Wo proj (compacted, gathered, split-4)
  gemm64_c<4, 1><<<dim3(8, 64, 4), 256, 0, stream>>>(attn_o, Wo_t, 1024, 1024, 256,
                                                     scr, nullptr, idxL, McPtr);
  // 7. compacted reduce + gate + residual + LN2
  ln2_fused_kernel<<<4096, 256, 0, stream>>>(scr, q_x, n2_w, mod, idxL, McPtr,
                                             xbuf_c, xn_c);
  // 8. MLP up + gelu (compacted)
  gemm64_c<1, 0><<<dim3(32, 64, 1), 256, 0, stream>>>(xn_c, W1_t, 4096, 1024, 1024,
                                                      h1, b1, idxL, McPtr);
  // 9. MLP down (compacted, split-4) + final reduce
  gemm64_c<4, 0><<<dim3(8, 64, 4), 256, 0, stream>>>(h1, W2_t, 1024, 4096, 1024,
                                                     scr, nullptr, idxL, McPtr);
  final_reduce_kernel<<<4096, 256, 0, stream>>>(scr, b2, mod, idxL, McPtr, xbuf_c, out);
}